// Round 1
// baseline (372.355 us; speedup 1.0000x reference)
//
#include <hip/hip_runtime.h>
#include <hip/hip_bf16.h>
#include <math.h>

// Problem constants (reference: M=256, D=768, THRESH=0.3, EPS=1e-8)
#define M 256
#define D 768
#define D4 (D/4)          // 192
#define THRESH 0.3
#define EPS 1e-8

// Workspace layout (floats):
//   [0..255]      Sm        (row sums of mem)
//   [256..511]    nm2       (row sumsq of mem)
//   [512..767]    kx        (dot(mem_i, x))
//   [768..1023]   nm_s      (max(||mem_i||, EPS))
//   [1024..1279]  mx_cos
//   [1280..1535]  w         (mask_i / nm_s_i)
//   [1536..1791]  A1
//   [1792..2047]  maskf
//   [2048..2815]  v[768]
//   [2816]  Sx   [2817] nx2   [2818] nx   [2819] cnt   [2820] A2
//   [3072..3072+65535]  s[a*256+i]
#define WS_SM    0
#define WS_NM2   256
#define WS_KX    512
#define WS_NMS   768
#define WS_MX    1024
#define WS_W     1280
#define WS_A1    1536
#define WS_MASK  1792
#define WS_V     2048
#define WS_SX    2816
#define WS_NX2   2817
#define WS_NX    2818
#define WS_CNT   2819
#define WS_A2    2820
#define WS_S     3072

// ---- Kernel 1: per-row stats of mem (blocks 0..255) and of x (block 256) ----
__global__ void row_stats_kernel(const float* __restrict__ x,
                                 const float* __restrict__ mem,
                                 float* __restrict__ ws) {
    const int r = blockIdx.x;
    const int t = threadIdx.x;
    const float* row = (r < M) ? (mem + (size_t)r * D) : x;

    double s = 0.0, sq = 0.0, dt = 0.0;
    for (int d = t; d < D; d += 256) {
        double m = (double)row[d];
        double xv = (double)x[d];
        s += m; sq += m * m; dt += m * xv;
    }
    __shared__ double sh0[256], sh1[256], sh2[256];
    sh0[t] = s; sh1[t] = sq; sh2[t] = dt;
    __syncthreads();
    for (int k = 128; k > 0; k >>= 1) {
        if (t < k) { sh0[t] += sh0[t + k]; sh1[t] += sh1[t + k]; sh2[t] += sh2[t + k]; }
        __syncthreads();
    }
    if (t == 0) {
        if (r < M) {
            ws[WS_SM + r]  = (float)sh0[0];
            ws[WS_NM2 + r] = (float)sh1[0];
            ws[WS_KX + r]  = (float)sh2[0];
        } else {
            ws[WS_SX]  = (float)sh0[0];   // Sx
            ws[WS_NX2] = (float)sh1[0];   // ||x||^2
        }
    }
}

// ---- Kernel 2: per-i derived stats + scalars (single block) ----
__global__ void stats2_kernel(float* __restrict__ ws) {
    const int i = threadIdx.x;
    double nx = sqrt(fmax((double)ws[WS_NX2], 0.0));
    nx = fmax(nx, EPS);
    double nm2 = (double)ws[WS_NM2 + i];
    double nm  = sqrt(fmax(nm2, 0.0));
    double nms = fmax(nm, EPS);
    double mx  = (double)ws[WS_KX + i] / (nms * nx);
    double mask = (mx > THRESH) ? 1.0 : 0.0;
    double w = mask / nms;

    ws[WS_NMS + i]  = (float)nms;
    ws[WS_MX + i]   = (float)mx;
    ws[WS_W + i]    = (float)w;
    ws[WS_MASK + i] = (float)mask;

    __shared__ double shc[256], sha[256];
    shc[i] = mask;
    sha[i] = mask * (double)ws[WS_SM + i] / nms;
    __syncthreads();
    for (int k = 128; k > 0; k >>= 1) {
        if (i < k) { shc[i] += shc[i + k]; sha[i] += sha[i + k]; }
        __syncthreads();
    }
    if (i == 0) {
        ws[WS_NX]  = (float)nx;
        ws[WS_CNT] = (float)shc[0];
        ws[WS_A2]  = (float)sha[0];
    }
}

// ---- Kernel 3: v[d] = sum_j w_j * mem[j,d]  (3 blocks x 256 threads) ----
__global__ void compute_v_kernel(const float* __restrict__ mem, float* __restrict__ ws) {
    const int d = blockIdx.x * 256 + threadIdx.x;  // 0..767
    __shared__ float wsh[M];
    if (threadIdx.x < M) wsh[threadIdx.x] = ws[WS_W + threadIdx.x];
    __syncthreads();
    double acc = 0.0;
    for (int j = 0; j < M; ++j)
        acc += (double)wsh[j] * (double)mem[(size_t)j * D + d];
    ws[WS_V + d] = (float)acc;
}

// ---- Kernel 4: A1[i] = dot(mem_i, v)  (256 blocks x 256 threads) ----
__global__ void compute_A1_kernel(const float* __restrict__ mem, float* __restrict__ ws) {
    const int i = blockIdx.x, t = threadIdx.x;
    double acc = 0.0;
    for (int d = t; d < D; d += 256)
        acc += (double)mem[(size_t)i * D + d] * (double)ws[WS_V + d];
    __shared__ double sh[256];
    sh[t] = acc;
    __syncthreads();
    for (int k = 128; k > 0; k >>= 1) {
        if (t < k) sh[t] += sh[t + k];
        __syncthreads();
    }
    if (t == 0) ws[WS_A1 + i] = (float)sh[0];
}

// ---- Kernel 5: s[a,i] = c + cos_kp_x + mean_cos_km  (block=a, thread=i) ----
__global__ void compute_s_kernel(const float* __restrict__ mem, float* __restrict__ ws) {
    const int a = blockIdx.x, i = threadIdx.x;
    __shared__ float4 arow[D4];
    if (i < D4) arow[i] = ((const float4*)(mem + (size_t)a * D))[i];
    __syncthreads();

    const float4* rowi = (const float4*)(mem + (size_t)i * D);
    double km = 0.0;
    for (int d = 0; d < D4; ++d) {
        float4 m = rowi[d];
        float4 av = arow[d];
        km += (double)m.x * av.x + (double)m.y * av.y
            + (double)m.z * av.z + (double)m.w * av.w;
    }
    double nmsa = (double)ws[WS_NMS + a];
    double nmsi = (double)ws[WS_NMS + i];
    double c = km / (nmsa * nmsi) + (double)ws[WS_MX + i];

    double nm2 = (double)ws[WS_NM2 + i];
    double Sm  = (double)ws[WS_SM + i];
    double kx  = (double)ws[WS_KX + i];
    double nkp = sqrt(fmax(nm2 + 2.0 * c * Sm + (double)D * c * c, EPS * EPS));

    double nx  = (double)ws[WS_NX];
    double Sx  = (double)ws[WS_SX];
    double cos_kp_x = (kx + c * Sx) / (nkp * nx);

    double cnt = (double)ws[WS_CNT];
    double A2  = (double)ws[WS_A2];
    double A1  = (double)ws[WS_A1 + i];
    double mean_cos_km = (cnt > 0.0) ? (A1 + c * A2) / (nkp * fmax(cnt, 1.0)) : 0.0;

    ws[WS_S + a * M + i] = (float)(c + cos_kp_x + mean_cos_km);
}

// ---- Kernel 6: out[a,i,:] = mask[a] ? mem[i,:] + s[a,i] + noise[a,i,:] : 0 ----
__global__ __launch_bounds__(D4) void final_kernel(const float* __restrict__ mem,
                                                   const float* __restrict__ noise,
                                                   const float* __restrict__ ws,
                                                   float* __restrict__ out) {
    const int i = blockIdx.x;   // memory index
    const int a = blockIdx.y;   // active-row index
    const int t = threadIdx.x;  // 0..191 (float4 chunk)
    const size_t idx = ((size_t)(a * M + i)) * D4 + t;

    float4 o;
    if (ws[WS_MASK + a] != 0.0f) {
        const float s = ws[WS_S + a * M + i];
        float4 m = ((const float4*)mem)[(size_t)i * D4 + t];
        float4 n = ((const float4*)noise)[idx];
        o.x = m.x + s + n.x;
        o.y = m.y + s + n.y;
        o.z = m.z + s + n.z;
        o.w = m.w + s + n.w;
    } else {
        o = make_float4(0.f, 0.f, 0.f, 0.f);
    }
    ((float4*)out)[idx] = o;
}

extern "C" void kernel_launch(void* const* d_in, const int* in_sizes, int n_in,
                              void* d_out, int out_size, void* d_ws, size_t ws_size,
                              hipStream_t stream) {
    const float* x     = (const float*)d_in[0];   // [1, D]
    const float* mem   = (const float*)d_in[1];   // [M, D]
    const float* noise = (const float*)d_in[2];   // [M, M, D]
    float* out = (float*)d_out;
    float* ws  = (float*)d_ws;

    row_stats_kernel<<<dim3(M + 1), dim3(256), 0, stream>>>(x, mem, ws);
    stats2_kernel<<<dim3(1), dim3(256), 0, stream>>>(ws);
    compute_v_kernel<<<dim3(3), dim3(256), 0, stream>>>(mem, ws);
    compute_A1_kernel<<<dim3(M), dim3(256), 0, stream>>>(mem, ws);
    compute_s_kernel<<<dim3(M), dim3(256), 0, stream>>>(mem, ws);
    final_kernel<<<dim3(M, M), dim3(D4), 0, stream>>>(mem, noise, ws, out);
}

// Round 2
// 338.255 us; speedup vs baseline: 1.1008x; 1.1008x over previous
//
#include <hip/hip_runtime.h>
#include <hip/hip_bf16.h>
#include <math.h>

#define M 256
#define D 768
#define D4 (D/4)          // 192
#define THRESH 0.3
#define EPS 1e-8

typedef float vfloat4 __attribute__((ext_vector_type(4)));

// Workspace layout (floats):
#define WS_SM    0      // [256] row sums of mem
#define WS_NM2   256    // [256] row sumsq
#define WS_KX    512    // [256] dot(mem_i, x)
#define WS_NMS   768    // [256] max(||mem_i||, EPS)
#define WS_MX    1024   // [256] mx_cos
#define WS_W     1280   // [256] mask/nms
#define WS_MASK  1536   // [256] mask
#define WS_SX    1792
#define WS_NX2   1793
#define WS_NX    1794
#define WS_CNT   1795
#define WS_A2    1796
#define WS_MEMT  2048             // [768*256] mem transposed: memT[d*M + i]
#define WS_ST    (2048 + D * M)   // [256*256] sT[i*M + a] = s[a,i]

// ---- K1: per-row stats (blocks 0..255) + x stats (block 256) + transpose ----
__global__ void k1_stats_transpose(const float* __restrict__ x,
                                   const float* __restrict__ mem,
                                   float* __restrict__ ws) {
    const int r = blockIdx.x;
    const int t = threadIdx.x;
    const float* row = (r < M) ? (mem + (size_t)r * D) : x;

    double s = 0.0, sq = 0.0, dt = 0.0;
    for (int d = t; d < D; d += 256) {
        float mf = row[d];
        double m = (double)mf;
        double xv = (double)x[d];
        s += m; sq += m * m; dt += m * xv;
        if (r < M) ws[WS_MEMT + d * M + r] = mf;   // scatter transpose (786 KB total)
    }
    __shared__ double sh0[256], sh1[256], sh2[256];
    sh0[t] = s; sh1[t] = sq; sh2[t] = dt;
    __syncthreads();
    for (int k = 128; k > 0; k >>= 1) {
        if (t < k) { sh0[t] += sh0[t + k]; sh1[t] += sh1[t + k]; sh2[t] += sh2[t + k]; }
        __syncthreads();
    }
    if (t == 0) {
        if (r < M) {
            ws[WS_SM + r]  = (float)sh0[0];
            ws[WS_NM2 + r] = (float)sh1[0];
            ws[WS_KX + r]  = (float)sh2[0];
        } else {
            ws[WS_SX]  = (float)sh0[0];
            ws[WS_NX2] = (float)sh1[0];
        }
    }
}

// ---- K2: derived per-i stats + scalars (1 block) ----
__global__ void k2_derived(float* __restrict__ ws) {
    const int i = threadIdx.x;
    double nx = sqrt(fmax((double)ws[WS_NX2], 0.0));
    nx = fmax(nx, EPS);
    double nm2 = (double)ws[WS_NM2 + i];
    double nm  = sqrt(fmax(nm2, 0.0));
    double nms = fmax(nm, EPS);
    double mx  = (double)ws[WS_KX + i] / (nms * nx);
    double mask = (mx > THRESH) ? 1.0 : 0.0;

    ws[WS_NMS + i]  = (float)nms;
    ws[WS_MX + i]   = (float)mx;
    ws[WS_W + i]    = (float)(mask / nms);
    ws[WS_MASK + i] = (float)mask;

    __shared__ double shc[256], sha[256];
    shc[i] = mask;
    sha[i] = mask * (double)ws[WS_SM + i] / nms;
    __syncthreads();
    for (int k = 128; k > 0; k >>= 1) {
        if (i < k) { shc[i] += shc[i + k]; sha[i] += sha[i + k]; }
        __syncthreads();
    }
    if (i == 0) {
        ws[WS_NX]  = (float)nx;
        ws[WS_CNT] = (float)shc[0];
        ws[WS_A2]  = (float)sha[0];
    }
}

// ---- K3: block i computes Gram row g[a]=dot(mem_i,mem_a) (coalesced via memT),
//          reduces A1[i] = sum_a w[a]*g[a], then s[a,i] -> sT[i*M+a] ----
__global__ __launch_bounds__(256) void k3_s(const float* __restrict__ mem,
                                            float* __restrict__ ws) {
    const int i = blockIdx.x;
    const int a = threadIdx.x;

    __shared__ float lrow[D];
    for (int d = a; d < D; d += 256) lrow[d] = mem[(size_t)i * D + d];
    __syncthreads();

    const float* memT = ws + WS_MEMT;
    float acc0 = 0.f, acc1 = 0.f, acc2 = 0.f, acc3 = 0.f;
    #pragma unroll 4
    for (int d = 0; d < D; d += 4) {
        acc0 += memT[(d + 0) * M + a] * lrow[d + 0];
        acc1 += memT[(d + 1) * M + a] * lrow[d + 1];
        acc2 += memT[(d + 2) * M + a] * lrow[d + 2];
        acc3 += memT[(d + 3) * M + a] * lrow[d + 3];
    }
    const double g = (double)((acc0 + acc1) + (acc2 + acc3));   // km_dot[i,a]

    // A1[i] = sum_a w[a] * g[a]
    __shared__ double shr[256];
    shr[a] = (double)ws[WS_W + a] * g;
    __syncthreads();
    for (int k = 128; k > 0; k >>= 1) {
        if (a < k) shr[a] += shr[a + k];
        __syncthreads();
    }
    const double A1 = shr[0];

    // i-uniform stats
    const double nmsi = (double)ws[WS_NMS + i];
    const double nm2  = (double)ws[WS_NM2 + i];
    const double Sm   = (double)ws[WS_SM + i];
    const double kx   = (double)ws[WS_KX + i];
    const double mxi  = (double)ws[WS_MX + i];
    const double nx   = (double)ws[WS_NX];
    const double Sx   = (double)ws[WS_SX];
    const double cnt  = (double)ws[WS_CNT];
    const double A2   = (double)ws[WS_A2];

    const double nmsa = (double)ws[WS_NMS + a];
    const double c = g / (nmsa * nmsi) + mxi;

    const double nkp = sqrt(fmax(nm2 + 2.0 * c * Sm + (double)D * c * c, EPS * EPS));
    const double cos_kp_x = (kx + c * Sx) / (nkp * nx);
    const double mean_cos_km = (cnt > 0.0) ? (A1 + c * A2) / (nkp * fmax(cnt, 1.0)) : 0.0;

    ws[WS_ST + i * M + a] = (float)(c + cos_kp_x + mean_cos_km);
}

// ---- K4: out[a,i,:] = mask[a] ? mem[i,:] + s[a,i] + noise[a,i,:] : 0 ----
__global__ __launch_bounds__(D4) void k4_final(const float* __restrict__ mem,
                                               const float* __restrict__ noise,
                                               const float* __restrict__ ws,
                                               float* __restrict__ out) {
    const int i = blockIdx.x;
    const int a = blockIdx.y;
    const int t = threadIdx.x;  // 0..191
    const size_t idx = ((size_t)(a * M + i)) * D4 + t;

    vfloat4 o;
    if (ws[WS_MASK + a] != 0.0f) {
        const float s = ws[WS_ST + i * M + a];
        vfloat4 m = ((const vfloat4*)mem)[(size_t)i * D4 + t];
        vfloat4 n = __builtin_nontemporal_load((const vfloat4*)noise + idx);
        o.x = m.x + s + n.x;
        o.y = m.y + s + n.y;
        o.z = m.z + s + n.z;
        o.w = m.w + s + n.w;
    } else {
        o = (vfloat4){0.f, 0.f, 0.f, 0.f};
    }
    __builtin_nontemporal_store(o, (vfloat4*)out + idx);
}

extern "C" void kernel_launch(void* const* d_in, const int* in_sizes, int n_in,
                              void* d_out, int out_size, void* d_ws, size_t ws_size,
                              hipStream_t stream) {
    const float* x     = (const float*)d_in[0];   // [1, D]
    const float* mem   = (const float*)d_in[1];   // [M, D]
    const float* noise = (const float*)d_in[2];   // [M, M, D]
    float* out = (float*)d_out;
    float* ws  = (float*)d_ws;

    k1_stats_transpose<<<dim3(M + 1), dim3(256), 0, stream>>>(x, mem, ws);
    k2_derived<<<dim3(1), dim3(256), 0, stream>>>(ws);
    k3_s<<<dim3(M), dim3(256), 0, stream>>>(mem, ws);
    k4_final<<<dim3(M, M), dim3(D4), 0, stream>>>(mem, noise, ws, out);
}